// Round 6
// baseline (2942.573 us; speedup 1.0000x reference)
//
#include <hip/hip_runtime.h>
#include <hip/hip_fp16.h>

typedef _Float16 f16;
typedef _Float16 f16x2 __attribute__((ext_vector_type(2)));
typedef _Float16 f16x8 __attribute__((ext_vector_type(8)));
typedef float    f32x4 __attribute__((ext_vector_type(4)));
typedef unsigned int u32;
typedef unsigned long long u64;

#define BN_EPS 1e-5f

static constexpr int BB  = 32;    // batch
static constexpr int CC  = 128;   // channels
static constexpr int HWN = 1024;  // H*W = L
static constexpr int RIN = 256;
static constexpr int RH  = 512;
static constexpr int OCN = 128;

// ---------------------------------------------------------------- BN stats
__global__ void bn_stats_kernel(const float* __restrict__ x,
                                const float* __restrict__ gamma,
                                const float* __restrict__ beta,
                                float* __restrict__ scale,
                                float* __restrict__ shift) {
    int c = blockIdx.x;
    int tid = threadIdx.x;
    float s = 0.f, s2 = 0.f;
    const float* xc = x + (size_t)c * HWN;
    for (int idx = tid; idx < BB * HWN; idx += 256) {
        int b = idx >> 10, hw = idx & 1023;
        float v = xc[(size_t)b * (CC * HWN) + hw];
        s += v; s2 += v * v;
    }
    for (int off = 32; off > 0; off >>= 1) {
        s  += __shfl_down(s, off, 64);
        s2 += __shfl_down(s2, off, 64);
    }
    __shared__ float ls[4], ls2[4];
    int wv = tid >> 6, ln = tid & 63;
    if (ln == 0) { ls[wv] = s; ls2[wv] = s2; }
    __syncthreads();
    if (tid == 0) {
        float ts  = ls[0] + ls[1] + ls[2] + ls[3];
        float ts2 = ls2[0] + ls2[1] + ls2[2] + ls2[3];
        const float inv_n = 1.0f / (BB * HWN);
        float mean = ts * inv_n;
        float var  = ts2 * inv_n - mean * mean;
        float rstd = rsqrtf(var + BN_EPS);
        float sc = gamma[c] * rstd;
        scale[c] = sc;
        shift[c] = beta[c] - mean * sc;
    }
}

// ------------------------------------------- normalize + transpose -> A1 f16
__global__ void prep_x_kernel(const float* __restrict__ x,
                              const float* __restrict__ scale,
                              const float* __restrict__ shift,
                              f16* __restrict__ A1) {
    __shared__ float tile[32][33];
    int tx = threadIdx.x, ty = threadIdx.y;  // 32 x 8
    int hb = blockIdx.x, cb = blockIdx.y, b = blockIdx.z;
    #pragma unroll
    for (int k = 0; k < 4; k++) {
        int c  = cb * 32 + ty + 8 * k;
        int hw = hb * 32 + tx;
        tile[ty + 8 * k][tx] = x[(size_t)b * (CC * HWN) + (size_t)c * HWN + hw];
    }
    __syncthreads();
    #pragma unroll
    for (int k = 0; k < 4; k++) {
        int hw = hb * 32 + ty + 8 * k;
        int c  = cb * 32 + tx;
        float v = tile[tx][ty + 8 * k];
        A1[(size_t)(b * HWN + hw) * CC + c] = (f16)(v * scale[c] + shift[c]);
    }
}

// ------------------------------------------------------------ weight prep
// wr layout for the batch-per-CU rnn: u32 idx = (slot*512 + t)*4 + e,
// slot = 8j + i (j = thread-local row 0..7, i = dwordx4 index 0..7).
// Thread t: rows 8*(t>>3)+j, col-chunk c = t&7 (h-pairs [32c, 32c+32)).
// Element e of dwordx4 i covers h-pair p = 32c + 4*(i XOR c) + e — the XOR
// folds the LDS bank-conflict-free h-read swizzle into the weight order.
// A wave's simultaneous (slot) loads are contiguous 16B/lane -> coalesced.
__global__ void prep_w_kernel(const float* __restrict__ w_in,
                              const float* __restrict__ w_ih,
                              const float* __restrict__ w_out,
                              const float* __restrict__ w_hh,
                              const float* __restrict__ b_ih,
                              const float* __restrict__ b_hh,
                              f16* __restrict__ w_in_h,
                              f16* __restrict__ w_ih_h,
                              f16* __restrict__ w_out_h,
                              u32* __restrict__ wr,
                              float* __restrict__ bihh) {
    int idx = blockIdx.x * 256 + threadIdx.x;
    if (idx < 32768) { w_in_h[idx] = (f16)w_in[idx]; return; }
    idx -= 32768;
    if (idx < 131072) { w_ih_h[idx] = (f16)w_ih[idx]; return; }
    idx -= 131072;
    if (idx < 65536) { w_out_h[idx] = (f16)w_out[idx]; return; }
    idx -= 65536;
    if (idx < 131072) {
        int e = idx & 3, q = idx >> 2;
        int t = q & 511, slot = q >> 9;      // slot 0..63
        int i = slot & 7, j = slot >> 3;     // i: dwordx4, j: local row
        int c = t & 7, g = t >> 3;
        int row = (g << 3) + j;              // output row 0..511
        int p = (c << 5) + ((i ^ c) << 2) + e;  // h-pair index
        f16 lo = (f16)w_hh[(size_t)row * 512 + 2 * p];
        f16 hi = (f16)w_hh[(size_t)row * 512 + 2 * p + 1];
        wr[idx] = (u32)__builtin_bit_cast(unsigned short, lo) |
                  ((u32)__builtin_bit_cast(unsigned short, hi) << 16);
        return;
    }
    idx -= 131072;
    if (idx < 512) { bihh[idx] = b_ih[idx] + b_hh[idx]; return; }
}

// ------------------------------------------------------------- MFMA GEMM
template <int MODE>
__global__ void gemm_kernel(const f16* __restrict__ A,
                            const f16* __restrict__ W,
                            const float* __restrict__ bias,
                            void* __restrict__ outp,
                            int N, int K) {
    int wave = threadIdx.x >> 6;
    int lane = threadIdx.x & 63;
    int q = lane >> 4, r = lane & 15;
    int bm = blockIdx.x * 256 + wave * 64;
    int bn = blockIdx.y * 64;

    f32x4 acc[4][4];
    #pragma unroll
    for (int i = 0; i < 4; i++)
        #pragma unroll
        for (int j = 0; j < 4; j++)
            acc[i][j] = (f32x4){0.f, 0.f, 0.f, 0.f};

    const f16* Ap = A + (size_t)(bm + r) * K + 8 * q;
    const f16* Wp = W + (size_t)(bn + r) * K + 8 * q;

    for (int k = 0; k < K; k += 32) {
        f16x8 av[4], bv[4];
        #pragma unroll
        for (int i = 0; i < 4; i++)
            av[i] = *(const f16x8*)(Ap + (size_t)(16 * i) * K + k);
        #pragma unroll
        for (int i = 0; i < 4; i++)
            bv[i] = *(const f16x8*)(Wp + (size_t)(16 * i) * K + k);
        #pragma unroll
        for (int mi = 0; mi < 4; mi++)
            #pragma unroll
            for (int ni = 0; ni < 4; ni++)
                acc[mi][ni] = __builtin_amdgcn_mfma_f32_16x16x32_f16(
                    av[mi], bv[ni], acc[mi][ni], 0, 0, 0);
    }

    #pragma unroll
    for (int mi = 0; mi < 4; mi++) {
        #pragma unroll
        for (int ni = 0; ni < 4; ni++) {
            int col = bn + 16 * ni + r;
            float bval = bias[col];
            #pragma unroll
            for (int i = 0; i < 4; i++) {
                int row = bm + 16 * mi + 4 * q + i;
                float val = acc[mi][ni][i] + bval;
                if (MODE == 0) {
                    val = val - tanhf(val);
                    ((f16*)outp)[(size_t)row * N + col] = (f16)val;
                } else if (MODE == 1) {
                    ((f16*)outp)[(size_t)row * N + col] = (f16)val;
                } else {
                    int b = row >> 10, hw = row & 1023;
                    ((float*)outp)[(size_t)b * (OCN * HWN) + (size_t)col * HWN + hw] = val;
                }
            }
        }
    }
}

// ---------------------------------------------------------------- RNN scan
// R6 redesign: ONE BATCH PER CU -> zero cross-WG communication.
// Evidence R0-R5: per-step cost was dominated by the cross-WG agent-scope
// publish->detect RT (~2000+ cyc, a coherence-fabric floor; the sc0 L2
// shortcut is not HW-coherent -> R5 fail). This kernel removes the exchange
// entirely: 32 WGs x 512 threads, WG = batch, thread t = row t.
//  * lanes c=t&7 split 512 cols into 8 chunks; per thread 8 rows x 32 dot2.
//  * W_hh 512KB/WG: rows j=0..3 register-resident (128 u32, asm-pinned,
//    budget 256 via waves_per_eu(2,2)); rows j=4..7 streamed from L2 each
//    step (32 coalesced dwordx4 = 256KB/WG/step, L2-hot, hidden under
//    ~1024cyc of dot2 issue). Streamed loads are kept per-iteration by
//    poisoning the 8 offset regs with an empty asm volatile (kills LICM).
//  * h in LDS, parity double-buffer, ONE __syncthreads per step.
//  * h reads: 8 ds_read_b128, XOR-swizzled (folded into weight pack) ->
//    8 distinct bank groups + broadcast -> conflict-free.
//  * butterfly reduce-scatter over the 8 chunk lanes (11 shfl + cndmask):
//    lane t ends with exactly row t's full sum -> tanh -> write.
__device__ __forceinline__ float dot2acc(u32 w, f16x2 h, float c) {
#if __has_builtin(__builtin_amdgcn_fdot2)
    return __builtin_amdgcn_fdot2(__builtin_bit_cast(f16x2, w), h, c, false);
#else
    f16x2 a = __builtin_bit_cast(f16x2, w);
    return c + (float)a[0] * (float)h[0] + (float)a[1] * (float)h[1];
#endif
}

__device__ __forceinline__ f16x2 u2h(u32 w) { return __builtin_bit_cast(f16x2, w); }

// resident: load slot n, unpack, pin
#define RQ(n)  uint4 Q##n = wr4[((size_t)(n) << 9) + t];
#define UP(n)  u32 W##n##x = Q##n.x, W##n##y = Q##n.y, W##n##z = Q##n.z, W##n##w = Q##n.w;
#define PIN(n) asm volatile("" : "+v"(W##n##x), "+v"(W##n##y), "+v"(W##n##z), "+v"(W##n##w));

// dot2 of one resident slot (4 u32 words) against one h-quad
#define D4(ACC, Wn, Qh)                                           \
    ACC = dot2acc(Wn##x, u2h(Qh.x), ACC);                         \
    ACC = dot2acc(Wn##y, u2h(Qh.y), ACC);                         \
    ACC = dot2acc(Wn##z, u2h(Qh.z), ACC);                         \
    ACC = dot2acc(Wn##w, u2h(Qh.w), ACC);
#define DROW_R(ACC, n0,n1,n2,n3,n4,n5,n6,n7)                      \
    D4(ACC, W##n0, q0) D4(ACC, W##n1, q1) D4(ACC, W##n2, q2)      \
    D4(ACC, W##n3, q3) D4(ACC, W##n4, q4) D4(ACC, W##n5, q5)      \
    D4(ACC, W##n6, q6) D4(ACC, W##n7, q7)

// streamed: dot2 of one loaded uint4 against one h-quad
#define DS4(ACC, S, Qh)                                           \
    ACC = dot2acc(S.x, u2h(Qh.x), ACC);                           \
    ACC = dot2acc(S.y, u2h(Qh.y), ACC);                           \
    ACC = dot2acc(S.z, u2h(Qh.z), ACC);                           \
    ACC = dot2acc(S.w, u2h(Qh.w), ACC);
#define SLD(v, base)                                              \
    uint4 v##0 = *(const uint4*)(base + o0);                      \
    uint4 v##1 = *(const uint4*)(base + o1);                      \
    uint4 v##2 = *(const uint4*)(base + o2);                      \
    uint4 v##3 = *(const uint4*)(base + o3);                      \
    uint4 v##4 = *(const uint4*)(base + o4);                      \
    uint4 v##5 = *(const uint4*)(base + o5);                      \
    uint4 v##6 = *(const uint4*)(base + o6);                      \
    uint4 v##7 = *(const uint4*)(base + o7);
#define DROW_S(ACC, v)                                            \
    DS4(ACC, v##0, q0) DS4(ACC, v##1, q1) DS4(ACC, v##2, q2)      \
    DS4(ACC, v##3, q3) DS4(ACC, v##4, q4) DS4(ACC, v##5, q5)      \
    DS4(ACC, v##6, q6) DS4(ACC, v##7, q7)

__global__ void __launch_bounds__(512)
__attribute__((amdgpu_waves_per_eu(2, 2)))
rnn_kernel(const u32* WR, f16* __restrict__ xh) {
    const int b = blockIdx.x;     // batch
    const int t = threadIdx.x;    // row t (finalize); c = col chunk
    const int c = t & 7;

    __shared__ __align__(16) f16 hbuf[2][512];

    const uint4* wr4 = (const uint4*)WR;
    // ---- resident rows j=0..3 (slots 0..31): 128 u32, pinned
    RQ(0)  RQ(1)  RQ(2)  RQ(3)  RQ(4)  RQ(5)  RQ(6)  RQ(7)
    RQ(8)  RQ(9)  RQ(10) RQ(11) RQ(12) RQ(13) RQ(14) RQ(15)
    RQ(16) RQ(17) RQ(18) RQ(19) RQ(20) RQ(21) RQ(22) RQ(23)
    RQ(24) RQ(25) RQ(26) RQ(27) RQ(28) RQ(29) RQ(30) RQ(31)
    UP(0)  UP(1)  UP(2)  UP(3)  UP(4)  UP(5)  UP(6)  UP(7)
    UP(8)  UP(9)  UP(10) UP(11) UP(12) UP(13) UP(14) UP(15)
    UP(16) UP(17) UP(18) UP(19) UP(20) UP(21) UP(22) UP(23)
    UP(24) UP(25) UP(26) UP(27) UP(28) UP(29) UP(30) UP(31)
    PIN(0)  PIN(1)  PIN(2)  PIN(3)  PIN(4)  PIN(5)  PIN(6)  PIN(7)
    PIN(8)  PIN(9)  PIN(10) PIN(11) PIN(12) PIN(13) PIN(14) PIN(15)
    PIN(16) PIN(17) PIN(18) PIN(19) PIN(20) PIN(21) PIN(22) PIN(23)
    PIN(24) PIN(25) PIN(26) PIN(27) PIN(28) PIN(29) PIN(30) PIN(31)

    ((u32*)hbuf)[t] = 0u;   // zero both parities (512 u32 = 2KB)
    __syncthreads();

    f16* xg = xh + (size_t)b * (HWN * RH);

    // streamed rows j=4..7: SGPR bases + 8 per-thread offsets (poisoned/iter)
    const char* sb4 = (const char*)WR + 262144;   // slot 32
    const char* sb5 = sb4 + 65536;                // slot 40
    const char* sb6 = sb4 + 131072;               // slot 48
    const char* sb7 = sb4 + 196608;               // slot 56
    u32 o0 = (u32)(t << 4);
    u32 o1 = o0 + 8192,  o2 = o0 + 16384, o3 = o0 + 24576,
        o4 = o0 + 32768, o5 = o0 + 40960, o6 = o0 + 49152, o7 = o0 + 57344;

    const char* hb0 = (const char*)&hbuf[0][0];
    const int cb = c << 7;
    const bool s0 = (c & 1) != 0, s1 = (c & 2) != 0, s2 = (c & 4) != 0;

    for (int step = 0; step < HWN; step++) {
        // poison offsets -> streamed loads cannot be hoisted out of the loop
        asm volatile("" : "+v"(o0), "+v"(o1), "+v"(o2), "+v"(o3),
                          "+v"(o4), "+v"(o5), "+v"(o6), "+v"(o7));
        SLD(v4, sb4) SLD(v5, sb5) SLD(v6, sb6) SLD(v7, sb7)

        float xcur = (float)xg[(size_t)step * RH + t];   // used at the end

        const char* hb = hb0 + ((step & 1) << 10);
        uint4 q0 = *(const uint4*)(hb + (cb | (((0) ^ c) << 4)));
        uint4 q1 = *(const uint4*)(hb + (cb | (((1) ^ c) << 4)));
        uint4 q2 = *(const uint4*)(hb + (cb | (((2) ^ c) << 4)));
        uint4 q3 = *(const uint4*)(hb + (cb | (((3) ^ c) << 4)));
        uint4 q4 = *(const uint4*)(hb + (cb | (((4) ^ c) << 4)));
        uint4 q5 = *(const uint4*)(hb + (cb | (((5) ^ c) << 4)));
        uint4 q6 = *(const uint4*)(hb + (cb | (((6) ^ c) << 4)));
        uint4 q7 = *(const uint4*)(hb + (cb | (((7) ^ c) << 4)));

        float a0 = 0.f, a1 = 0.f, a2 = 0.f, a3 = 0.f;
        DROW_R(a0, 0,1,2,3,4,5,6,7)
        DROW_R(a1, 8,9,10,11,12,13,14,15)
        DROW_R(a2, 16,17,18,19,20,21,22,23)
        DROW_R(a3, 24,25,26,27,28,29,30,31)
        float a4 = 0.f, a5 = 0.f, a6 = 0.f, a7 = 0.f;
        DROW_S(a4, v4) DROW_S(a5, v5) DROW_S(a6, v6) DROW_S(a7, v7)

        // ---- butterfly reduce-scatter over the 8 chunk lanes:
        // lane c ends with the full sum for local row j == c (global row t).
        float x01 = __shfl_xor(s0 ? a0 : a1, 1, 64);
        float n01 = (s0 ? a1 : a0) + x01;
        float x23 = __shfl_xor(s0 ? a2 : a3, 1, 64);
        float n23 = (s0 ? a3 : a2) + x23;
        float x45 = __shfl_xor(s0 ? a4 : a5, 1, 64);
        float n45 = (s0 ? a5 : a4) + x45;
        float x67 = __shfl_xor(s0 ? a6 : a7, 1, 64);
        float n67 = (s0 ? a7 : a6) + x67;

        float xA = __shfl_xor(s1 ? n01 : n23, 2, 64);
        float mA = (s1 ? n23 : n01) + xA;
        float xB = __shfl_xor(s1 ? n45 : n67, 2, 64);
        float mB = (s1 ? n67 : n45) + xB;

        float xC = __shfl_xor(s2 ? mA : mB, 4, 64);
        float my = (s2 ? mB : mA) + xC;

        float h = tanhf(xcur + my);
        f16 hf = (f16)h;
        hbuf[(step & 1) ^ 1][t] = hf;          // next-step h
        xg[(size_t)step * RH + t] = hf;        // hs output (in place)
        __syncthreads();
    }
}

// ------------------------------------------------------------------ launch
extern "C" void kernel_launch(void* const* d_in, const int* in_sizes, int n_in,
                              void* d_out, int out_size, void* d_ws, size_t ws_size,
                              hipStream_t stream) {
    const float* x     = (const float*)d_in[0];
    const float* gamma = (const float*)d_in[1];
    const float* beta  = (const float*)d_in[2];
    const float* w_in  = (const float*)d_in[3];
    const float* b_in  = (const float*)d_in[4];
    const float* w_ih  = (const float*)d_in[5];
    const float* b_ih  = (const float*)d_in[6];
    const float* w_hh  = (const float*)d_in[7];
    const float* b_hh  = (const float*)d_in[8];
    const float* w_out = (const float*)d_in[9];
    const float* b_out = (const float*)d_in[10];

    char* ws = (char*)d_ws;
    float* scale   = (float*)(ws + 0);         //   512 B
    float* shift   = (float*)(ws + 512);       //   512 B
    float* bihh    = (float*)(ws + 1024);      //  2 KB
    f16*   w_in_h  = (f16*)(ws + 4096);        // 64 KB
    f16*   w_ih_h  = (f16*)(ws + 69632);       // 256 KB
    f16*   w_out_h = (f16*)(ws + 331776);      // 128 KB
    u32*   wr      = (u32*)(ws + 462848);      // 512 KB packed W_hh
    f16*   xh      = (f16*)(ws + 1179648);     // 32 MB xgate, overwritten by hs
    f16*   A1      = (f16*)(ws + 34734080);    //  8 MB
    f16*   inp     = (f16*)(ws + 43122688);    // 16 MB (ends 59899904)

    bn_stats_kernel<<<128, 256, 0, stream>>>(x, gamma, beta, scale, shift);
    prep_w_kernel<<<1410, 256, 0, stream>>>(w_in, w_ih, w_out, w_hh, b_ih, b_hh,
                                            w_in_h, w_ih_h, w_out_h, wr, bihh);
    prep_x_kernel<<<dim3(32, 4, 32), dim3(32, 8), 0, stream>>>(x, scale, shift, A1);
    gemm_kernel<0><<<dim3(128, 4), 256, 0, stream>>>(A1, w_in_h, b_in, (void*)inp, RIN, CC);
    gemm_kernel<1><<<dim3(128, 8), 256, 0, stream>>>(inp, w_ih_h, bihh, (void*)xh, RH, RIN);
    rnn_kernel<<<32, 512, 0, stream>>>(wr, xh);
    gemm_kernel<2><<<dim3(128, 2), 256, 0, stream>>>(xh, w_out_h, b_out, d_out, OCN, RH);
}

// Round 7
// 2352.104 us; speedup vs baseline: 1.2510x; 1.2510x over previous
//
#include <hip/hip_runtime.h>
#include <hip/hip_fp16.h>

typedef _Float16 f16;
typedef _Float16 f16x2 __attribute__((ext_vector_type(2)));
typedef _Float16 f16x8 __attribute__((ext_vector_type(8)));
typedef float    f32x4 __attribute__((ext_vector_type(4)));
typedef unsigned int u32;
typedef unsigned long long u64;

#define BN_EPS 1e-5f

static constexpr int BB  = 32;    // batch
static constexpr int CC  = 128;   // channels
static constexpr int HWN = 1024;  // H*W = L
static constexpr int RIN = 256;
static constexpr int RH  = 512;
static constexpr int OCN = 128;

// ---------------------------------------------------------------- BN stats
__global__ void bn_stats_kernel(const float* __restrict__ x,
                                const float* __restrict__ gamma,
                                const float* __restrict__ beta,
                                float* __restrict__ scale,
                                float* __restrict__ shift) {
    int c = blockIdx.x;
    int tid = threadIdx.x;
    float s = 0.f, s2 = 0.f;
    const float* xc = x + (size_t)c * HWN;
    for (int idx = tid; idx < BB * HWN; idx += 256) {
        int b = idx >> 10, hw = idx & 1023;
        float v = xc[(size_t)b * (CC * HWN) + hw];
        s += v; s2 += v * v;
    }
    for (int off = 32; off > 0; off >>= 1) {
        s  += __shfl_down(s, off, 64);
        s2 += __shfl_down(s2, off, 64);
    }
    __shared__ float ls[4], ls2[4];
    int wv = tid >> 6, ln = tid & 63;
    if (ln == 0) { ls[wv] = s; ls2[wv] = s2; }
    __syncthreads();
    if (tid == 0) {
        float ts  = ls[0] + ls[1] + ls[2] + ls[3];
        float ts2 = ls2[0] + ls2[1] + ls2[2] + ls2[3];
        const float inv_n = 1.0f / (BB * HWN);
        float mean = ts * inv_n;
        float var  = ts2 * inv_n - mean * mean;
        float rstd = rsqrtf(var + BN_EPS);
        float sc = gamma[c] * rstd;
        scale[c] = sc;
        shift[c] = beta[c] - mean * sc;
    }
}

// ------------------------------------------- normalize + transpose -> A1 f16
__global__ void prep_x_kernel(const float* __restrict__ x,
                              const float* __restrict__ scale,
                              const float* __restrict__ shift,
                              f16* __restrict__ A1) {
    __shared__ float tile[32][33];
    int tx = threadIdx.x, ty = threadIdx.y;  // 32 x 8
    int hb = blockIdx.x, cb = blockIdx.y, b = blockIdx.z;
    #pragma unroll
    for (int k = 0; k < 4; k++) {
        int c  = cb * 32 + ty + 8 * k;
        int hw = hb * 32 + tx;
        tile[ty + 8 * k][tx] = x[(size_t)b * (CC * HWN) + (size_t)c * HWN + hw];
    }
    __syncthreads();
    #pragma unroll
    for (int k = 0; k < 4; k++) {
        int hw = hb * 32 + ty + 8 * k;
        int c  = cb * 32 + tx;
        float v = tile[tx][ty + 8 * k];
        A1[(size_t)(b * HWN + hw) * CC + c] = (f16)(v * scale[c] + shift[c]);
    }
}

// ------------------------------------------------------------ weight prep
// wr layout (same as R6, correctness-verified): u32 idx = (slot*512+t)*4+e,
// slot = 8j+i. Thread t: rows 8*(t>>3)+j, chunk c=t&7 (h-pairs [32c,32c+32)).
// Element e of dwordx4 i covers h-pair p = 32c + 4*(i XOR c) + e.
__global__ void prep_w_kernel(const float* __restrict__ w_in,
                              const float* __restrict__ w_ih,
                              const float* __restrict__ w_out,
                              const float* __restrict__ w_hh,
                              const float* __restrict__ b_ih,
                              const float* __restrict__ b_hh,
                              f16* __restrict__ w_in_h,
                              f16* __restrict__ w_ih_h,
                              f16* __restrict__ w_out_h,
                              u32* __restrict__ wr,
                              float* __restrict__ bihh) {
    int idx = blockIdx.x * 256 + threadIdx.x;
    if (idx < 32768) { w_in_h[idx] = (f16)w_in[idx]; return; }
    idx -= 32768;
    if (idx < 131072) { w_ih_h[idx] = (f16)w_ih[idx]; return; }
    idx -= 131072;
    if (idx < 65536) { w_out_h[idx] = (f16)w_out[idx]; return; }
    idx -= 65536;
    if (idx < 131072) {
        int e = idx & 3, q = idx >> 2;
        int t = q & 511, slot = q >> 9;      // slot 0..63
        int i = slot & 7, j = slot >> 3;     // i: dwordx4, j: local row
        int c = t & 7, g = t >> 3;
        int row = (g << 3) + j;              // output row 0..511
        int p = (c << 5) + ((i ^ c) << 2) + e;  // h-pair index
        f16 lo = (f16)w_hh[(size_t)row * 512 + 2 * p];
        f16 hi = (f16)w_hh[(size_t)row * 512 + 2 * p + 1];
        wr[idx] = (u32)__builtin_bit_cast(unsigned short, lo) |
                  ((u32)__builtin_bit_cast(unsigned short, hi) << 16);
        return;
    }
    idx -= 131072;
    if (idx < 512) { bihh[idx] = b_ih[idx] + b_hh[idx]; return; }
}

// ------------------------------------------------------------- MFMA GEMM
template <int MODE>
__global__ void gemm_kernel(const f16* __restrict__ A,
                            const f16* __restrict__ W,
                            const float* __restrict__ bias,
                            void* __restrict__ outp,
                            int N, int K) {
    int wave = threadIdx.x >> 6;
    int lane = threadIdx.x & 63;
    int q = lane >> 4, r = lane & 15;
    int bm = blockIdx.x * 256 + wave * 64;
    int bn = blockIdx.y * 64;

    f32x4 acc[4][4];
    #pragma unroll
    for (int i = 0; i < 4; i++)
        #pragma unroll
        for (int j = 0; j < 4; j++)
            acc[i][j] = (f32x4){0.f, 0.f, 0.f, 0.f};

    const f16* Ap = A + (size_t)(bm + r) * K + 8 * q;
    const f16* Wp = W + (size_t)(bn + r) * K + 8 * q;

    for (int k = 0; k < K; k += 32) {
        f16x8 av[4], bv[4];
        #pragma unroll
        for (int i = 0; i < 4; i++)
            av[i] = *(const f16x8*)(Ap + (size_t)(16 * i) * K + k);
        #pragma unroll
        for (int i = 0; i < 4; i++)
            bv[i] = *(const f16x8*)(Wp + (size_t)(16 * i) * K + k);
        #pragma unroll
        for (int mi = 0; mi < 4; mi++)
            #pragma unroll
            for (int ni = 0; ni < 4; ni++)
                acc[mi][ni] = __builtin_amdgcn_mfma_f32_16x16x32_f16(
                    av[mi], bv[ni], acc[mi][ni], 0, 0, 0);
    }

    #pragma unroll
    for (int mi = 0; mi < 4; mi++) {
        #pragma unroll
        for (int ni = 0; ni < 4; ni++) {
            int col = bn + 16 * ni + r;
            float bval = bias[col];
            #pragma unroll
            for (int i = 0; i < 4; i++) {
                int row = bm + 16 * mi + 4 * q + i;
                float val = acc[mi][ni][i] + bval;
                if (MODE == 0) {
                    val = val - tanhf(val);
                    ((f16*)outp)[(size_t)row * N + col] = (f16)val;
                } else if (MODE == 1) {
                    ((f16*)outp)[(size_t)row * N + col] = (f16)val;
                } else {
                    int b = row >> 10, hw = row & 1023;
                    ((float*)outp)[(size_t)b * (OCN * HWN) + (size_t)col * HWN + hw] = val;
                }
            }
        }
    }
}

// ---------------------------------------------------------------- RNN scan
// R7: batch-per-CU (zero cross-WG comm, R6-verified math) with W_hh split
// across the three fast tiers. R6 post-mortem: VGPR 88 again -> the 32
// upfront streamed uint4 (128 VGPR) + 128 pinned exceeded 256 -> spill; and
// 256KB/step L2 streaming is port-limited anyway. Placement now:
//  * rows j=0..4 (320KB): register-resident, 160 u32/thread, asm-pinned.
//  * rows j=5,6 (128KB): LDS, quad-swizzled slot (q+t)&15 -> even 8
//    words/bank per wave b128 read (the 8-cyc hardware minimum).
//  * row  j=7  (64KB/step): streamed from L2, two 4-quad halves -> only
//    16 stream VGPRs live. Offset poisoned per iter (LICM guard).
//  * k-loop over 8 h-quads: 1 h-quad live (4 VGPR) instead of 32; lane
//    reads quad k^c at step k -> 8 distinct quads across c-groups ->
//    conflict-free broadcast.
// Peak live ~215 < 256 budget (waves_per_eu(2,2)). Verify VGPR>=200.
__device__ __forceinline__ float dot2acc(u32 w, f16x2 h, float c) {
#if __has_builtin(__builtin_amdgcn_fdot2)
    return __builtin_amdgcn_fdot2(__builtin_bit_cast(f16x2, w), h, c, false);
#else
    f16x2 a = __builtin_bit_cast(f16x2, w);
    return c + (float)a[0] * (float)h[0] + (float)a[1] * (float)h[1];
#endif
}

__device__ __forceinline__ f16x2 u2h(u32 w) { return __builtin_bit_cast(f16x2, w); }

// load + name + pin one resident weight quad (row j, k-slot k)
#define LW(j,k)                                                              \
    uint4 Q##j##k = wr4[(((j) * 8 + (k)) << 9) + t];                         \
    u32 W##j##k##x = Q##j##k.x, W##j##k##y = Q##j##k.y,                      \
        W##j##k##z = Q##j##k.z, W##j##k##w = Q##j##k.w;                      \
    asm volatile("" : "+v"(W##j##k##x), "+v"(W##j##k##y),                    \
                      "+v"(W##j##k##z), "+v"(W##j##k##w));

#define DOT4(ACC, WN, H)                                                     \
    ACC = dot2acc(WN##x, u2h(H.x), ACC);                                     \
    ACC = dot2acc(WN##y, u2h(H.y), ACC);                                     \
    ACC = dot2acc(WN##z, u2h(H.z), ACC);                                     \
    ACC = dot2acc(WN##w, u2h(H.w), ACC);

#define DOTQ(ACC, V, H)                                                      \
    ACC = dot2acc(V.x, u2h(H.x), ACC);                                       \
    ACC = dot2acc(V.y, u2h(H.y), ACC);                                       \
    ACC = dot2acc(V.z, u2h(H.z), ACC);                                       \
    ACC = dot2acc(V.w, u2h(H.w), ACC);

// one k-step: h-quad k^c, LDS rows j=5,6 at swizzled slots, stream row j=7
#define KSTEP(k, SV)                                                         \
{   uint4 hq = *(const uint4*)(hb + (c << 7) + (((k) ^ c) << 4));            \
    uint4 w5 = *(const uint4*)(wl + (((((k)      ) + t) & 15) << 4));        \
    uint4 w6 = *(const uint4*)(wl + (((((k) +  8 ) + t) & 15) << 4));        \
    DOT4(a0, W0##k, hq) DOT4(a1, W1##k, hq) DOT4(a2, W2##k, hq)              \
    DOT4(a3, W3##k, hq) DOT4(a4, W4##k, hq)                                  \
    DOTQ(a5, w5, hq) DOTQ(a6, w6, hq) DOTQ(a7, SV, hq) }

__global__ void __launch_bounds__(512)
__attribute__((amdgpu_waves_per_eu(2, 2)))
rnn_kernel(const u32* WR, f16* __restrict__ xh) {
    const int b = blockIdx.x;     // batch
    const int t = threadIdx.x;    // finalize row t; chunk c = t&7
    const int c = t & 7;

    // [0,512): h double-buffer (2 parities x 256 u32); [512,33280): weights
    __shared__ __align__(16) u32 shm[33280];   // 130 KB

    const uint4* wr4 = (const uint4*)WR;

    // ---- resident rows j=0..4 (slots 0..39): 160 u32, pinned
    LW(0,0) LW(0,1) LW(0,2) LW(0,3) LW(0,4) LW(0,5) LW(0,6) LW(0,7)
    LW(1,0) LW(1,1) LW(1,2) LW(1,3) LW(1,4) LW(1,5) LW(1,6) LW(1,7)
    LW(2,0) LW(2,1) LW(2,2) LW(2,3) LW(2,4) LW(2,5) LW(2,6) LW(2,7)
    LW(3,0) LW(3,1) LW(3,2) LW(3,3) LW(3,4) LW(3,5) LW(3,6) LW(3,7)
    LW(4,0) LW(4,1) LW(4,2) LW(4,3) LW(4,4) LW(4,5) LW(4,6) LW(4,7)

    // ---- rows j=5,6 (slots 40..55) -> LDS, quad-swizzled (q+t)&15
    char* wldst = (char*)shm + 2048 + (t << 8);
    #pragma unroll
    for (int q = 0; q < 16; q++) {
        uint4 v = wr4[((40 + q) << 9) + t];
        *(uint4*)(wldst + (((q + t) & 15) << 4)) = v;
    }
    shm[t] = 0u;                  // zero both h parities (512 u32)
    __syncthreads();

    f16* xg = xh + (size_t)b * (HWN * RH);
    const char* wl    = (const char*)shm + 2048 + (t << 8);
    const char* hbase = (const char*)shm;
    const uint4* s7   = wr4 + (56 << 9);    // row j=7 (slots 56..63)
    const bool s0 = (c & 1) != 0, s1 = (c & 2) != 0, s2 = (c & 4) != 0;

    for (int step = 0; step < HWN; step++) {
        // LICM guard: stream base poisoned -> loads stay inside the loop
        unsigned long long s7a = (unsigned long long)s7;
        asm volatile("" : "+v"(s7a));
        const uint4* s7v = (const uint4*)s7a;
        uint4 v0 = s7v[t],          v1 = s7v[512 + t],
              v2 = s7v[1024 + t],   v3 = s7v[1536 + t];

        float xcur = (float)xg[(size_t)step * RH + t];

        const char* hb = hbase + ((step & 1) << 10);
        float a0 = 0.f, a1 = 0.f, a2 = 0.f, a3 = 0.f;
        float a4 = 0.f, a5 = 0.f, a6 = 0.f, a7 = 0.f;

        KSTEP(0, v0) KSTEP(1, v1)
        uint4 v4 = s7v[2048 + t], v5 = s7v[2560 + t],
              v6 = s7v[3072 + t], v7 = s7v[3584 + t];
        KSTEP(2, v2) KSTEP(3, v3)
        KSTEP(4, v4) KSTEP(5, v5) KSTEP(6, v6) KSTEP(7, v7)

        // ---- butterfly reduce-scatter (R6-verified): lane c gets row j==c
        float x01 = __shfl_xor(s0 ? a0 : a1, 1, 64);
        float n01 = (s0 ? a1 : a0) + x01;
        float x23 = __shfl_xor(s0 ? a2 : a3, 1, 64);
        float n23 = (s0 ? a3 : a2) + x23;
        float x45 = __shfl_xor(s0 ? a4 : a5, 1, 64);
        float n45 = (s0 ? a5 : a4) + x45;
        float x67 = __shfl_xor(s0 ? a6 : a7, 1, 64);
        float n67 = (s0 ? a7 : a6) + x67;

        float xA = __shfl_xor(s1 ? n01 : n23, 2, 64);
        float mA = (s1 ? n23 : n01) + xA;
        float xB = __shfl_xor(s1 ? n45 : n67, 2, 64);
        float mB = (s1 ? n67 : n45) + xB;

        float xC = __shfl_xor(s2 ? mA : mB, 4, 64);
        float my = (s2 ? mB : mA) + xC;

        float h = tanhf(xcur + my);
        f16 hf = (f16)h;
        ((f16*)(hbase + (((step & 1) ^ 1) << 10)))[t] = hf;   // next-step h
        xg[(size_t)step * RH + t] = hf;                        // hs output
        __syncthreads();
    }
}

// ------------------------------------------------------------------ launch
extern "C" void kernel_launch(void* const* d_in, const int* in_sizes, int n_in,
                              void* d_out, int out_size, void* d_ws, size_t ws_size,
                              hipStream_t stream) {
    const float* x     = (const float*)d_in[0];
    const float* gamma = (const float*)d_in[1];
    const float* beta  = (const float*)d_in[2];
    const float* w_in  = (const float*)d_in[3];
    const float* b_in  = (const float*)d_in[4];
    const float* w_ih  = (const float*)d_in[5];
    const float* b_ih  = (const float*)d_in[6];
    const float* w_hh  = (const float*)d_in[7];
    const float* b_hh  = (const float*)d_in[8];
    const float* w_out = (const float*)d_in[9];
    const float* b_out = (const float*)d_in[10];

    char* ws = (char*)d_ws;
    float* scale   = (float*)(ws + 0);         //   512 B
    float* shift   = (float*)(ws + 512);       //   512 B
    float* bihh    = (float*)(ws + 1024);      //  2 KB
    f16*   w_in_h  = (f16*)(ws + 4096);        // 64 KB
    f16*   w_ih_h  = (f16*)(ws + 69632);       // 256 KB
    f16*   w_out_h = (f16*)(ws + 331776);      // 128 KB
    u32*   wr      = (u32*)(ws + 462848);      // 512 KB packed W_hh
    f16*   xh      = (f16*)(ws + 1179648);     // 32 MB xgate, overwritten by hs
    f16*   A1      = (f16*)(ws + 34734080);    //  8 MB
    f16*   inp     = (f16*)(ws + 43122688);    // 16 MB (ends 59899904)

    bn_stats_kernel<<<128, 256, 0, stream>>>(x, gamma, beta, scale, shift);
    prep_w_kernel<<<1410, 256, 0, stream>>>(w_in, w_ih, w_out, w_hh, b_ih, b_hh,
                                            w_in_h, w_ih_h, w_out_h, wr, bihh);
    prep_x_kernel<<<dim3(32, 4, 32), dim3(32, 8), 0, stream>>>(x, scale, shift, A1);
    gemm_kernel<0><<<dim3(128, 4), 256, 0, stream>>>(A1, w_in_h, b_in, (void*)inp, RIN, CC);
    gemm_kernel<1><<<dim3(128, 8), 256, 0, stream>>>(inp, w_ih_h, bihh, (void*)xh, RH, RIN);
    rnn_kernel<<<32, 512, 0, stream>>>(wr, xh);
    gemm_kernel<2><<<dim3(128, 2), 256, 0, stream>>>(xh, w_out_h, b_out, d_out, OCN, RH);
}